// Round 3
// baseline (871.940 us; speedup 1.0000x reference)
//
#include <hip/hip_runtime.h>

// Problem constants
#define BB   64
#define NN   4096
#define EE   8192
#define DD   256
#define HH   256
#define MM   64
#define K1   512          // 2*D
#define NC   384          // H + 128 (fused GEMM1 cols: 256 h | 128 g)
#define TE   128          // edges per block
#define BLOCK 512         // threads per block (8 waves)
#define KC   32           // K elems per chunk
#define NCHUNK 16         // K1 / KC
#define ASTR 40           // 32 + 8 pad (bf16 elems; 80B row, 16B multiple)
#define BSTR 40
#define GSTR 136          // 128 + 8 pad (272B row, 16B multiple)
#define BE_TOT (BB * EE)  // 524288
#define WS_NEEDED ((size_t)(NC * K1 + MM * 128) * sizeof(short))  // 409600 B

typedef float f32x4 __attribute__((ext_vector_type(4)));
typedef short bf16x8 __attribute__((ext_vector_type(8)));

__device__ __forceinline__ short f2bf(float f) {
    unsigned u = __float_as_uint(f);
    unsigned r = (u + 0x7fffu + ((u >> 16) & 1u)) >> 16;
    return (short)r;
}

// Prep: transpose+convert weights to bf16 in workspace (fast path only).
// wct[n][k] = (n<256 ? W1[k][n] : A1[k][n-256]), n in [0,384), k in [0,512)
// a2t[n][k] = A2[k][n], n in [0,64), k in [0,128)
__global__ void AttackHead_prep(const float* __restrict__ W1,
                                const float* __restrict__ A1,
                                const float* __restrict__ A2,
                                short* __restrict__ wct,
                                short* __restrict__ a2t) {
    int idx = blockIdx.x * 256 + threadIdx.x;
    if (idx < NC * K1) {
        int n = idx >> 9, k = idx & 511;
        float v = (n < HH) ? W1[k * HH + n] : A1[k * 128 + (n - HH)];
        wct[idx] = f2bf(v);
    } else {
        int j = idx - NC * K1;
        if (j < MM * 128) {
            int n = j >> 7, k = j & 127;
            a2t[j] = f2bf(A2[k * MM + n]);
        }
    }
}

template <bool USE_WS>
__global__ __launch_bounds__(BLOCK, 2)
void AttackHead_main(const float* __restrict__ nodes,
                     const float* __restrict__ army,
                     const int* __restrict__ edges,
                     const float* __restrict__ W1,
                     const float* __restrict__ b1,
                     const float* __restrict__ W2,
                     const float* __restrict__ b2,
                     const float* __restrict__ A1,
                     const float* __restrict__ a1,
                     const float* __restrict__ A2,
                     const float* __restrict__ a2,
                     const short* __restrict__ wct,
                     const short* __restrict__ a2t,
                     float* __restrict__ out) {
    // Union LDS region, kept under the 64KB static-shared limit:
    //   GEMM1 phase: As[128][40] @0 (10240B) | Bs[384][40] @10240 (30720B) -> 40960B
    //   GEMM2 phase: Gs[128][136] @0 (34816B) | a2sh[64][136] @34816 (17408B) -> 52224B
    __shared__ __align__(16) char smem[52224];
    short* As   = (short*)smem;
    short* Bs   = (short*)(smem + 10240);
    short* Gs   = (short*)smem;
    short* a2sh = (short*)(smem + 34816);

    __shared__ int   srcn[TE], tgtn[TE];
    __shared__ float elog[TE], maxs[TE];
    __shared__ float bcomb[NC];   // b1 | a1
    __shared__ float W2s[HH];
    __shared__ float a2s[MM];

    const int tid  = threadIdx.x;
    const int bb   = blockIdx.x;
    const int bglob = bb / (EE / TE);       // batch index (uniform per block)
    const long be0 = (long)bb * TE;         // first flattened edge row

    // ---- Phase 0: scalars, biases ----
    for (int t = tid; t < NC; t += BLOCK) bcomb[t] = (t < HH) ? b1[t] : a1[t - HH];
    for (int t = tid; t < HH; t += BLOCK) W2s[t] = W2[t];
    for (int t = tid; t < MM; t += BLOCK) a2s[t] = a2[t];

    if (tid < TE) {
        long be = be0 + tid;
        int src = edges[2 * be], tgt = edges[2 * be + 1];
        int sc = min(max(src, 0), NN - 1);
        int tc = min(max(tgt, 0), NN - 1);
        srcn[tid] = sc; tgtn[tid] = tc;
        float sa = army[(size_t)bglob * NN + sc];
        float ta = army[(size_t)bglob * NN + tc];
        bool valid = (src >= 0) && (tgt >= 0);
        bool bad   = valid && (sa <= 2.0f || ta >= 3.0f * sa);
        bool selfe = valid && (src == tgt);
        elog[tid] = b2[0] - (bad ? 1.0f : 0.0f) - (selfe ? 100.0f : 0.0f);
        maxs[tid] = sa - 1.0f;
    }
    __syncthreads();

    const int w     = tid >> 6;        // wave 0..7
    const int lane  = tid & 63;
    const int quad  = lane >> 4;
    const int l15   = lane & 15;
    const int mhalf = w & 1;           // M-blocks mhalf*4 .. +3
    const int nbase = (w >> 1) * 6;    // 6 N-tiles per wave

    f32x4 acc[4][6] = {};

    // ---- GEMM1 K-chunk loop (16 chunks of K=32) ----
    for (int kc = 0; kc < NCHUNK; ++kc) {
        // stage A (gather + cvt): 128 rows x 32 k; each thread one 16B store
        {
            int row = tid >> 2;            // 0..127
            int j8  = tid & 3;             // 0..3
            int kl  = j8 * 8;
            int node = (kc < 8) ? srcn[row] : tgtn[row];   // chunk k-range never crosses D
            int koff = (kc & 7) * KC + kl;
            const float* p = nodes + ((size_t)bglob * NN + node) * DD + koff;
            float4 v0 = ((const float4*)p)[0];
            float4 v1 = ((const float4*)p)[1];
            short s[8];
            s[0] = f2bf(v0.x); s[1] = f2bf(v0.y); s[2] = f2bf(v0.z); s[3] = f2bf(v0.w);
            s[4] = f2bf(v1.x); s[5] = f2bf(v1.y); s[6] = f2bf(v1.z); s[7] = f2bf(v1.w);
            *(int4*)(&As[row * ASTR + kl]) = *(const int4*)s;
        }
        // stage B: 384 rows x 32 k; 3 x 16B per thread
        #pragma unroll
        for (int i = 0; i < 3; ++i) {
            int flat = tid + i * BLOCK;    // 0..1535
            int row = flat >> 2, j8 = flat & 3;
            if (USE_WS) {
                *(int4*)(&Bs[row * BSTR + j8 * 8]) =
                    *(const int4*)(wct + row * K1 + kc * KC + j8 * 8);
            } else {
                short tmp[8];
                #pragma unroll
                for (int jj = 0; jj < 8; ++jj) {
                    int k = kc * KC + j8 * 8 + jj;
                    float v = (row < HH) ? W1[k * HH + row] : A1[k * 128 + (row - HH)];
                    tmp[jj] = f2bf(v);
                }
                *(int4*)(&Bs[row * BSTR + j8 * 8]) = *(const int4*)tmp;
            }
        }
        __syncthreads();

        // MFMA: each wave 4 M-tiles x 6 N-tiles, K=32 per MFMA
        {
            bf16x8 af[4];
            #pragma unroll
            for (int im = 0; im < 4; ++im)
                af[im] = *(const bf16x8*)(&As[((mhalf * 4 + im) * 16 + l15) * ASTR + quad * 8]);
            #pragma unroll
            for (int jn = 0; jn < 6; ++jn) {
                bf16x8 bfv = *(const bf16x8*)(&Bs[((nbase + jn) * 16 + l15) * BSTR + quad * 8]);
                #pragma unroll
                for (int im = 0; im < 4; ++im)
                    acc[im][jn] = __builtin_amdgcn_mfma_f32_16x16x32_bf16(af[im], bfv, acc[im][jn], 0, 0, 0);
            }
        }
        __syncthreads();
    }

    // ---- Stage A2^T (bf16) into LDS for GEMM2 (Bs region is dead now) ----
    if (USE_WS) {
        #pragma unroll
        for (int i = 0; i < 2; ++i) {
            int c = tid + i * BLOCK;       // 0..1023
            int rn = c >> 4, j = c & 15;
            *(int4*)(&a2sh[rn * GSTR + j * 8]) = *(const int4*)(a2t + rn * 128 + j * 8);
        }
    } else {
        for (int t = tid; t < MM * 128; t += BLOCK) {
            int n = t >> 7, k = t & 127;
            a2sh[n * GSTR + k] = f2bf(A2[k * MM + n]);
        }
    }

    // ---- Epilogue 1: bias+relu; edge-logit partials; relu(g) -> Gs ----
    float ep[4][4] = {};
    #pragma unroll
    for (int jn = 0; jn < 6; ++jn) {
        int nb = nbase + jn;
        int col = nb * 16 + l15;
        float bias = bcomb[col];
        if (col < HH) {
            float w2v = W2s[col];
            #pragma unroll
            for (int im = 0; im < 4; ++im)
                #pragma unroll
                for (int r = 0; r < 4; ++r) {
                    float h = acc[im][jn][r] + bias;
                    h = fmaxf(h, 0.0f);
                    ep[im][r] += h * w2v;
                }
        } else {
            int gc = col - HH;
            #pragma unroll
            for (int im = 0; im < 4; ++im)
                #pragma unroll
                for (int r = 0; r < 4; ++r) {
                    float g = acc[im][jn][r] + bias;
                    g = fmaxf(g, 0.0f);
                    int grow = (mhalf * 4 + im) * 16 + quad * 4 + r;
                    Gs[grow * GSTR + gc] = f2bf(g);
                }
        }
    }
    // reduce edge-logit partials across the 16 lanes of each quad
    #pragma unroll
    for (int msk = 1; msk <= 8; msk <<= 1)
        #pragma unroll
        for (int im = 0; im < 4; ++im)
            #pragma unroll
            for (int r = 0; r < 4; ++r)
                ep[im][r] += __shfl_xor(ep[im][r], msk, 64);
    if (l15 == 0 && w < 6) {   // waves 6,7 have no cols < 256
        #pragma unroll
        for (int im = 0; im < 4; ++im)
            #pragma unroll
            for (int r = 0; r < 4; ++r)
                atomicAdd(&elog[(mhalf * 4 + im) * 16 + quad * 4 + r], ep[im][r]);
    }
    __syncthreads();

    // ---- GEMM2: relu(g)[128,128] @ A2[128,64]; wave w owns M-tile w ----
    f32x4 acc2[4] = {};
    #pragma unroll
    for (int ks = 0; ks < 4; ++ks) {
        bf16x8 ga = *(const bf16x8*)(&Gs[(w * 16 + l15) * GSTR + ks * 32 + quad * 8]);
        #pragma unroll
        for (int nb2 = 0; nb2 < 4; ++nb2) {
            bf16x8 bv = *(const bf16x8*)(&a2sh[(nb2 * 16 + l15) * GSTR + ks * 32 + quad * 8]);
            acc2[nb2] = __builtin_amdgcn_mfma_f32_16x16x32_bf16(ga, bv, acc2[nb2], 0, 0, 0);
        }
    }

    // ---- Write outputs ----
    if (tid < TE) out[be0 + tid] = elog[tid];

    #pragma unroll
    for (int nb2 = 0; nb2 < 4; ++nb2) {
        int col = nb2 * 16 + l15;
        float a2v = a2s[col];
        #pragma unroll
        for (int r = 0; r < 4; ++r) {
            int grow = w * 16 + quad * 4 + r;
            float val = acc2[nb2][r] + a2v;
            if ((float)col > maxs[grow]) val = -1e9f;
            out[(size_t)BE_TOT + (size_t)(be0 + grow) * MM + col] = val;
        }
    }
}

extern "C" void kernel_launch(void* const* d_in, const int* in_sizes, int n_in,
                              void* d_out, int out_size, void* d_ws, size_t ws_size,
                              hipStream_t stream) {
    const float* nodes = (const float*)d_in[0];
    const float* army  = (const float*)d_in[1];
    const int*   edges = (const int*)d_in[2];
    const float* W1    = (const float*)d_in[3];
    const float* b1    = (const float*)d_in[4];
    const float* W2    = (const float*)d_in[5];
    const float* b2    = (const float*)d_in[6];
    const float* A1    = (const float*)d_in[7];
    const float* a1    = (const float*)d_in[8];
    const float* A2    = (const float*)d_in[9];
    const float* a2    = (const float*)d_in[10];
    float* out = (float*)d_out;

    int nblocks = BE_TOT / TE;                 // 4096

    if (ws_size >= WS_NEEDED) {
        short* wct = (short*)d_ws;             // 384*512 bf16 = 393216 B
        short* a2t = wct + NC * K1;            // 64*128 bf16 = 16384 B
        int prep_elems = NC * K1 + MM * 128;
        AttackHead_prep<<<(prep_elems + 255) / 256, 256, 0, stream>>>(W1, A1, A2, wct, a2t);
        AttackHead_main<true><<<nblocks, BLOCK, 0, stream>>>(
            nodes, army, edges, W1, b1, W2, b2, A1, a1, A2, a2, wct, a2t, out);
    } else {
        AttackHead_main<false><<<nblocks, BLOCK, 0, stream>>>(
            nodes, army, edges, W1, b1, W2, b2, A1, a1, A2, a2,
            (const short*)nullptr, (const short*)nullptr, out);
    }
}

// Round 4
// 685.241 us; speedup vs baseline: 1.2725x; 1.2725x over previous
//
#include <hip/hip_runtime.h>

// Problem constants
#define BB   64
#define NN   4096
#define EE   8192
#define DD   256
#define HH   256
#define MM   64
#define K1   512          // 2*D
#define NC   384          // H + 128 fused GEMM1 cols
#define TE   64           // edges per block
#define BLOCK 512         // 8 waves
#define KC   32
#define NCHUNK 16         // K1/KC
#define ASTR 40           // shorts per A row (32 + 8 pad) -> 80B, 16B-aligned, 2-way banks
#define GSTR 136          // shorts per Gs row (128 + 8 pad)
#define ABUF 2560         // 64*40 shorts per A buffer
#define BE_TOT (BB * EE)  // 524288
#define WCTF_ELEMS (NC * K1)   // 196608
#define A2F_ELEMS  (128 * MM)  // 8192
#define WS_NEEDED ((size_t)(WCTF_ELEMS + A2F_ELEMS) * sizeof(short))  // 409600

typedef float f32x4 __attribute__((ext_vector_type(4)));
typedef short bf16x8 __attribute__((ext_vector_type(8)));

__device__ __forceinline__ short f2bf(float f) {
    unsigned u = __float_as_uint(f);
    unsigned r = (u + 0x7fffu + ((u >> 16) & 1u)) >> 16;
    return (short)r;
}

// Prep: write weights in MFMA B-fragment order (bf16).
// wctf frag (c,nt,lane): n = nt*16+(lane&15), k = c*32+(lane>>4)*8+j
//   flat = ((c*24+nt)*64+lane)*8 + j
// a2f  frag (ks,nt2,lane): n = nt2*16+(lane&15), k = ks*32+(lane>>4)*8+j
//   flat = ((ks*4+nt2)*64+lane)*8 + j
__global__ void AttackHead_prep(const float* __restrict__ W1,
                                const float* __restrict__ A1,
                                const float* __restrict__ A2,
                                short* __restrict__ wctf,
                                short* __restrict__ a2f) {
    int t = blockIdx.x * 256 + threadIdx.x;
    if (t < 131072) {                       // W1 [512][256], coalesced read
        int k = t >> 8, n = t & 255;
        int c = k >> 5, kr = k & 31, quad = kr >> 3, j = kr & 7;
        int nt = n >> 4, l15 = n & 15;
        wctf[((c * 24 + nt) * 64 + quad * 16 + l15) * 8 + j] = f2bf(W1[t]);
    } else if (t < 131072 + 65536) {        // A1 [512][128]
        int t2 = t - 131072;
        int k = t2 >> 7, n = 256 + (t2 & 127);
        int c = k >> 5, kr = k & 31, quad = kr >> 3, j = kr & 7;
        int nt = n >> 4, l15 = n & 15;
        wctf[((c * 24 + nt) * 64 + quad * 16 + l15) * 8 + j] = f2bf(A1[t2]);
    } else if (t < 131072 + 65536 + 8192) { // A2 [128][64]
        int t3 = t - 131072 - 65536;
        int k = t3 >> 6, n = t3 & 63;
        int ks = k >> 5, kr = k & 31, quad = kr >> 3, j = kr & 7;
        int nt2 = n >> 4, l15 = n & 15;
        a2f[((ks * 4 + nt2) * 64 + quad * 16 + l15) * 8 + j] = f2bf(A2[t3]);
    }
}

template <bool USE_WS>
__device__ __forceinline__ bf16x8 load_bfrag(const short* __restrict__ wf,
                                             const float* __restrict__ W1,
                                             const float* __restrict__ A1,
                                             int c, int nt, int lane) {
    if (USE_WS) {
        return *(const bf16x8*)(wf + ((c * 24 + nt) * 64 + lane) * 8);
    } else {
        int l15 = lane & 15, quad = lane >> 4;
        int n = nt * 16 + l15;
        bf16x8 r;
        #pragma unroll
        for (int j = 0; j < 8; ++j) {
            int k = c * KC + quad * 8 + j;
            float v = (n < HH) ? W1[k * HH + n] : A1[k * 128 + (n - HH)];
            r[j] = f2bf(v);
        }
        return r;
    }
}

template <bool USE_WS>
__device__ __forceinline__ bf16x8 load_a2frag(const short* __restrict__ a2f,
                                              const float* __restrict__ A2,
                                              int ks, int nt2, int lane) {
    if (USE_WS) {
        return *(const bf16x8*)(a2f + ((ks * 4 + nt2) * 64 + lane) * 8);
    } else {
        int l15 = lane & 15, quad = lane >> 4;
        int n = nt2 * 16 + l15;
        bf16x8 r;
        #pragma unroll
        for (int j = 0; j < 8; ++j) {
            int k = ks * 32 + quad * 8 + j;
            r[j] = f2bf(A2[k * MM + n]);
        }
        return r;
    }
}

template <bool USE_WS>
__global__ __launch_bounds__(BLOCK, 4)
void AttackHead_main(const float* __restrict__ nodes,
                     const float* __restrict__ army,
                     const int* __restrict__ edges,
                     const float* __restrict__ W1,
                     const float* __restrict__ b1,
                     const float* __restrict__ W2,
                     const float* __restrict__ b2,
                     const float* __restrict__ A1,
                     const float* __restrict__ a1,
                     const float* __restrict__ A2,
                     const float* __restrict__ a2,
                     const short* __restrict__ wctf,
                     const short* __restrict__ a2f,
                     float* __restrict__ out) {
    // LDS: union of {3 A-buffers (3*2560=7680 shorts)} and {Gs 64x136=8704 shorts}
    __shared__ __align__(16) short smem[8704];   // 17408 B
    __shared__ int   srcn[TE], tgtn[TE];
    __shared__ float elog[TE], maxs[TE];

    const int tid = threadIdx.x;
    const int bb  = blockIdx.x;
    const int bglob = bb >> 7;              // bb / (EE/TE) = bb/128
    const long be0 = (long)bb * TE;

    // ---- Phase 0: edge scalars ----
    if (tid < TE) {
        long be = be0 + tid;
        int src = edges[2 * be], tgt = edges[2 * be + 1];
        int sc = min(max(src, 0), NN - 1);
        int tc = min(max(tgt, 0), NN - 1);
        srcn[tid] = sc; tgtn[tid] = tc;
        float sa = army[(size_t)bglob * NN + sc];
        float ta = army[(size_t)bglob * NN + tc];
        bool valid = (src >= 0) && (tgt >= 0);
        bool bad   = valid && (sa <= 2.0f || ta >= 3.0f * sa);
        bool selfe = valid && (src == tgt);
        elog[tid] = b2[0] - (bad ? 1.0f : 0.0f) - (selfe ? 100.0f : 0.0f);
        maxs[tid] = sa - 1.0f;
    }
    __syncthreads();

    const int w    = tid >> 6;     // wave 0..7
    const int lane = tid & 63;
    const int quad = lane >> 4;
    const int l15  = lane & 15;

    // staging role: 8 threads per row, 4 floats each
    const int srow = tid >> 3;     // 0..63
    const int sj   = tid & 7;      // float4 index within 32-float chunk
    const size_t nbase_g = (size_t)bglob * NN;

    f32x4 acc[4][3] = {};          // [m-tile][n-tile] ; wave's n-tiles = w*3 + jn

    // ---- Prologue: stage chunk 0, issue chunk 1 ----
    {
        int node = srcn[srow];
        float4 v = *(const float4*)(nodes + (nbase_g + node) * DD + sj * 4);
        short4 s;
        s.x = f2bf(v.x); s.y = f2bf(v.y); s.z = f2bf(v.z); s.w = f2bf(v.w);
        *(short4*)(&smem[0 * ABUF + srow * ASTR + sj * 4]) = s;
    }
    float4 lda = *(const float4*)(nodes + (nbase_g + srcn[srow]) * DD + KC + sj * 4);

    int bufc = 0;
    for (int c = 0; c < NCHUNK; ++c) {
        __syncthreads();           // buf[bufc] ready; write-target safe

        // distance-2 prefetch: issue chunk c+2 gather
        float4 ldn;
        if (c + 2 < NCHUNK) {
            int cc = c + 2;
            int node = (cc < 8) ? srcn[srow] : tgtn[srow];
            ldn = *(const float4*)(nodes + (nbase_g + node) * DD + (cc & 7) * KC + sj * 4);
        }

        // B fragments (fragment-ordered, coalesced 1KB/wave-instr from L2)
        bf16x8 bf0 = load_bfrag<USE_WS>(wctf, W1, A1, c, w * 3 + 0, lane);
        bf16x8 bf1 = load_bfrag<USE_WS>(wctf, W1, A1, c, w * 3 + 1, lane);
        bf16x8 bf2 = load_bfrag<USE_WS>(wctf, W1, A1, c, w * 3 + 2, lane);

        // A fragments from LDS
        const short* Ab = &smem[bufc * ABUF];
        bf16x8 af[4];
        #pragma unroll
        for (int mt = 0; mt < 4; ++mt)
            af[mt] = *(const bf16x8*)(&Ab[(mt * 16 + l15) * ASTR + quad * 8]);

        #pragma unroll
        for (int mt = 0; mt < 4; ++mt) {
            acc[mt][0] = __builtin_amdgcn_mfma_f32_16x16x32_bf16(af[mt], bf0, acc[mt][0], 0, 0, 0);
            acc[mt][1] = __builtin_amdgcn_mfma_f32_16x16x32_bf16(af[mt], bf1, acc[mt][1], 0, 0, 0);
            acc[mt][2] = __builtin_amdgcn_mfma_f32_16x16x32_bf16(af[mt], bf2, acc[mt][2], 0, 0, 0);
        }

        // stage chunk c+1 into next buffer
        int bufw = (bufc + 1 == 3) ? 0 : bufc + 1;
        if (c + 1 < NCHUNK) {
            short4 s;
            s.x = f2bf(lda.x); s.y = f2bf(lda.y); s.z = f2bf(lda.z); s.w = f2bf(lda.w);
            *(short4*)(&smem[bufw * ABUF + srow * ASTR + sj * 4]) = s;
            lda = ldn;
        }
        bufc = bufw;
    }

    __syncthreads();   // all reads of A buffers done; Gs region reuse is safe

    // ---- Epilogue 1: bias+relu; edge-logit partials; relu(g) -> Gs ----
    short* Gs = smem;
    float ep[4][4] = {};
    #pragma unroll
    for (int jn = 0; jn < 3; ++jn) {
        int ct = (w * 3 + jn) * 16 + l15;
        float bias = (ct < HH) ? b1[ct] : a1[ct - HH];
        if (ct < HH) {
            float w2v = W2[ct];
            #pragma unroll
            for (int mt = 0; mt < 4; ++mt)
                #pragma unroll
                for (int r = 0; r < 4; ++r) {
                    float h = fmaxf(acc[mt][jn][r] + bias, 0.0f);
                    ep[mt][r] += h * w2v;
                }
        } else {
            int gc = ct - HH;
            #pragma unroll
            for (int mt = 0; mt < 4; ++mt)
                #pragma unroll
                for (int r = 0; r < 4; ++r) {
                    float g = fmaxf(acc[mt][jn][r] + bias, 0.0f);
                    Gs[(mt * 16 + quad * 4 + r) * GSTR + gc] = f2bf(g);
                }
        }
    }
    if (w < 6) {   // waves 6,7 have no h-columns
        #pragma unroll
        for (int msk = 1; msk <= 8; msk <<= 1)
            #pragma unroll
            for (int mt = 0; mt < 4; ++mt)
                #pragma unroll
                for (int r = 0; r < 4; ++r)
                    ep[mt][r] += __shfl_xor(ep[mt][r], msk, 64);
        if (l15 == 0) {
            #pragma unroll
            for (int mt = 0; mt < 4; ++mt)
                #pragma unroll
                for (int r = 0; r < 4; ++r)
                    atomicAdd(&elog[mt * 16 + quad * 4 + r], ep[mt][r]);
        }
    }
    __syncthreads();

    // ---- GEMM2: relu(g)[64,128] @ A2[128,64] ----
    const int mt2 = w >> 1;      // m-tile 0..3
    const int nh  = w & 1;       // n-half
    f32x4 acc2[2] = {};
    #pragma unroll
    for (int ks = 0; ks < 4; ++ks) {
        bf16x8 ga = *(const bf16x8*)(&Gs[(mt2 * 16 + l15) * GSTR + ks * 32 + quad * 8]);
        #pragma unroll
        for (int nb = 0; nb < 2; ++nb) {
            bf16x8 bv = load_a2frag<USE_WS>(a2f, A2, ks, nh * 2 + nb, lane);
            acc2[nb] = __builtin_amdgcn_mfma_f32_16x16x32_bf16(ga, bv, acc2[nb], 0, 0, 0);
        }
    }

    // ---- Outputs ----
    if (tid < TE) out[be0 + tid] = elog[tid];

    #pragma unroll
    for (int nb = 0; nb < 2; ++nb) {
        int col = (nh * 2 + nb) * 16 + l15;
        float a2v = a2[col];
        #pragma unroll
        for (int r = 0; r < 4; ++r) {
            int grow = mt2 * 16 + quad * 4 + r;
            float val = acc2[nb][r] + a2v;
            if ((float)col > maxs[grow]) val = -1e9f;
            out[(size_t)BE_TOT + (size_t)(be0 + grow) * MM + col] = val;
        }
    }
}

extern "C" void kernel_launch(void* const* d_in, const int* in_sizes, int n_in,
                              void* d_out, int out_size, void* d_ws, size_t ws_size,
                              hipStream_t stream) {
    const float* nodes = (const float*)d_in[0];
    const float* army  = (const float*)d_in[1];
    const int*   edges = (const int*)d_in[2];
    const float* W1    = (const float*)d_in[3];
    const float* b1    = (const float*)d_in[4];
    const float* W2    = (const float*)d_in[5];
    const float* b2    = (const float*)d_in[6];
    const float* A1    = (const float*)d_in[7];
    const float* a1    = (const float*)d_in[8];
    const float* A2    = (const float*)d_in[9];
    const float* a2    = (const float*)d_in[10];
    float* out = (float*)d_out;

    int nblocks = BE_TOT / TE;   // 8192

    if (ws_size >= WS_NEEDED) {
        short* wctf = (short*)d_ws;
        short* a2f  = wctf + WCTF_ELEMS;
        AttackHead_prep<<<800, 256, 0, stream>>>(W1, A1, A2, wctf, a2f);
        AttackHead_main<true><<<nblocks, BLOCK, 0, stream>>>(
            nodes, army, edges, W1, b1, W2, b2, A1, a1, A2, a2, wctf, a2f, out);
    } else {
        AttackHead_main<false><<<nblocks, BLOCK, 0, stream>>>(
            nodes, army, edges, W1, b1, W2, b2, A1, a1, A2, a2,
            (const short*)nullptr, (const short*)nullptr, out);
    }
}